// Round 14
// baseline (95.525 us; speedup 1.0000x reference)
//
#include <hip/hip_runtime.h>
#include <hip/hip_bf16.h>
#include <float.h>

#define N 4096
#define DF 256
#define NB2 2048
#define MAXM 128
#define NPUSHBLK 528

typedef __attribute__((ext_vector_type(8))) short short8v;
typedef __attribute__((ext_vector_type(8))) unsigned short ushort8v;
typedef __attribute__((ext_vector_type(4))) float floatx4;

__device__ inline unsigned short f2bf(float f) {
    __hip_bfloat16 h = __float2bfloat16(f);
    return *reinterpret_cast<unsigned short*>(&h);
}
__device__ inline float bf2f(unsigned short h) {
    unsigned int u = ((unsigned int)h) << 16;
    return __uint_as_float(u);
}

__device__ inline void gload_lds16(const void* g, void* l) {
    __builtin_amdgcn_global_load_lds((const __attribute__((address_space(1))) void*)g,
                                     (__attribute__((address_space(3))) void*)l, 16, 0, 0);
}

// merge two sorted triples (a holds result)
__device__ inline void merge3(float& a0, float& a1, float& a2, float b0, float b1, float b2) {
    float m0, m1, m2;
    if (a0 <= b0) {
        m0 = a0;
        if (a1 <= b0) { m1 = a1; m2 = fminf(a2, b0); }
        else { m1 = b0; m2 = fminf(a1, b1); }
    } else {
        m0 = b0;
        if (b1 <= a0) { m1 = b1; m2 = fminf(b2, a0); }
        else { m1 = a0; m2 = fminf(b1, a1); }
    }
    a0 = m0; a1 = m1; a2 = m2;
}

// ---------------- prep: x2 norms + bf16 convert + (extra block) class bucketing ----------------
__global__ __launch_bounds__(256) void prep_kernel(const float* __restrict__ X,
                                                   const int* __restrict__ labels,
                                                   float* __restrict__ x2,
                                                   __hip_bfloat16* __restrict__ Xb,
                                                   int* __restrict__ cnt,
                                                   int* __restrict__ members,
                                                   double* __restrict__ accd,
                                                   unsigned int* __restrict__ tickets,
                                                   int useXb) {
    int t = threadIdx.x;
    if (blockIdx.x == 1024) {
        __shared__ int scnt[64];
        if (t < 8) accd[t] = 0.0;
        if (t < 16) tickets[t] = 0u;
        if (t < 64) scnt[t] = 0;
        __syncthreads();
        for (int i = t; i < N; i += 256) {
            int c = labels[i];
            int pos = atomicAdd(&scnt[c], 1);
            if (pos < MAXM) members[(c << 8) + pos] = i;
        }
        __syncthreads();
        if (t < 64) cnt[t] = min(scnt[t], MAXM);
        return;
    }
    int row = blockIdx.x * 4 + (t >> 6);
    int l = t & 63;
    int idx = row * 64 + l;
    float4 v = ((const float4*)X)[idx];
    if (useXb) {
        ushort4 o;
        o.x = f2bf(v.x); o.y = f2bf(v.y); o.z = f2bf(v.z); o.w = f2bf(v.w);
        ((ushort4*)Xb)[idx] = o;
    }
    float s = v.x * v.x + v.y * v.y + v.z * v.z + v.w * v.w;
#pragma unroll
    for (int off = 32; off > 0; off >>= 1) s += __shfl_xor(s, off, 64);
    if (l == 0) x2[row] = s;
}

// ---------------- per-(class, col-quarter) partial 3-NN via hi/lo bf16 MFMA ----------------
__device__ inline void top3_upd(float& b0, float& b1, float& b2, float dd) {
    if (dd < b2) {
        if (dd < b1) { b2 = b1; if (dd < b0) { b1 = b0; b0 = dd; } else b1 = dd; }
        else b2 = dd;
    }
}

__global__ __launch_bounds__(512) void knn4_kernel(const float* __restrict__ X,
                                                   const float* __restrict__ x2,
                                                   const int* __restrict__ cnt,
                                                   const int* __restrict__ members,
                                                   float* __restrict__ ptop) {
    __shared__ __align__(16) char smem[32768];   // Hi 16 KB + Lo 16 KB (32 member rows)
    __shared__ int marr[MAXM];
    __shared__ float mx2[MAXM];

    int c = blockIdx.x & 63;
    int q = blockIdx.x >> 6;          // 0..3 column quarter
    int m = cnt[c];
    if (q * 32 >= m) return;          // block-uniform
    const int* mem = members + (c << 8);
    int tid = threadIdx.x;
    int lane = tid & 63;
    int wid = tid >> 6;
    int qbase = q * 32;

    if (tid < MAXM) {
        int mi = (tid < m) ? mem[tid] : -1;
        marr[tid] = mi;
        mx2[tid] = (mi >= 0) ? x2[mi] : 0.f;
    }
    __syncthreads();

    char* Hi = smem;
    char* Lo = smem + 16384;

#pragma unroll
    for (int it = 0; it < 2; ++it) {
        int idx = it * 512 + tid;
        int rb = idx >> 9;
        int rem = idx & 511;
        int kb = rem >> 4;
        int r0 = rem & 15;
        int rg = qbase + rb * 16 + r0;
        ushort8v vhi = (ushort8v){0,0,0,0,0,0,0,0};
        ushort8v vlo = vhi;
        if (rg < m) {
            const float4* src = (const float4*)(X + (size_t)marr[rg] * DF + kb * 8);
            float4 u0 = src[0], u1 = src[1];
            float uu[8] = {u0.x, u0.y, u0.z, u0.w, u1.x, u1.y, u1.z, u1.w};
#pragma unroll
            for (int p = 0; p < 8; ++p) {
                unsigned short h = f2bf(uu[p]);
                vhi[p] = h;
                vlo[p] = f2bf(uu[p] - bf2f(h));
            }
        }
        *((ushort8v*)(Hi + ((size_t)idx << 4))) = vhi;
        *((ushort8v*)(Lo + ((size_t)idx << 4))) = vlo;
    }
    __syncthreads();

    int nstripe = (m + 15) >> 4;
    if (wid >= nstripe) return;

    int arow = wid * 16 + (lane & 15);
    bool avalid = (arow < m);
    const float* aptr = X + (size_t)(avalid ? marr[arow] : 0) * DF;
    int ko = (lane >> 4) * 8;
    short8v aHi[8], aLo[8];
#pragma unroll
    for (int kk = 0; kk < 8; ++kk) {
        ushort8v vhi = (ushort8v){0,0,0,0,0,0,0,0};
        ushort8v vlo = vhi;
        if (avalid) {
            const float* p0 = aptr + kk * 32 + ko;
            float4 u0 = *(const float4*)p0;
            float4 u1 = *(const float4*)(p0 + 4);
            float uu[8] = {u0.x, u0.y, u0.z, u0.w, u1.x, u1.y, u1.z, u1.w};
#pragma unroll
            for (int p = 0; p < 8; ++p) {
                unsigned short h = f2bf(uu[p]);
                vhi[p] = h;
                vlo[p] = f2bf(uu[p] - bf2f(h));
            }
        }
        aHi[kk] = *(short8v*)&vhi;
        aLo[kk] = *(short8v*)&vlo;
    }

    int g = lane >> 4;
    int cl = lane & 15;
    float x2i[4];
#pragma unroll
    for (int r = 0; r < 4; ++r) {
        int il = wid * 16 + g * 4 + r;
        x2i[r] = mx2[il];
    }

    float t0[4], t1[4], t2[4];
#pragma unroll
    for (int r = 0; r < 4; ++r) { t0[r] = FLT_MAX; t1[r] = FLT_MAX; t2[r] = FLT_MAX; }

#pragma unroll
    for (int ct = 0; ct < 2; ++ct) {
        floatx4 acc = (floatx4){0.f, 0.f, 0.f, 0.f};
#pragma unroll
        for (int kk = 0; kk < 8; ++kk) {
            size_t off = (size_t)ct * 8192 + (size_t)kk * 1024 + ((size_t)lane << 4);
            short8v bHi = *((const short8v*)(Hi + off));
            short8v bLo = *((const short8v*)(Lo + off));
            acc = __builtin_amdgcn_mfma_f32_16x16x32_bf16(aLo[kk], bHi, acc, 0, 0, 0);
            acc = __builtin_amdgcn_mfma_f32_16x16x32_bf16(aHi[kk], bLo, acc, 0, 0, 0);
            acc = __builtin_amdgcn_mfma_f32_16x16x32_bf16(aHi[kk], bHi, acc, 0, 0, 0);
        }
        int jg = qbase + ct * 16 + cl;
        float x2j = (jg < MAXM) ? mx2[jg] : 0.f;
#pragma unroll
        for (int r = 0; r < 4; ++r) {
            int il = wid * 16 + g * 4 + r;
            float d = fmaxf(x2i[r] + x2j - 2.f * acc[r], 0.f);
            bool valid = (jg < m) && (il < m) && (jg != il);
            top3_upd(t0[r], t1[r], t2[r], valid ? d : FLT_MAX);
        }
    }

#pragma unroll
    for (int off = 1; off <= 8; off <<= 1) {
#pragma unroll
        for (int r = 0; r < 4; ++r) {
            float c0 = __shfl_xor(t0[r], off, 64);
            float c1 = __shfl_xor(t1[r], off, 64);
            float c2 = __shfl_xor(t2[r], off, 64);
            float m0, m1, m2;
            if (t0[r] <= c0) {
                m0 = t0[r];
                if (t1[r] <= c0) { m1 = t1[r]; m2 = fminf(t2[r], c0); }
                else { m1 = c0; m2 = fminf(t1[r], c1); }
            } else {
                m0 = c0;
                if (c1 <= t0[r]) { m1 = c1; m2 = fminf(c2, t0[r]); }
                else { m1 = t0[r]; m2 = fminf(c1, t1[r]); }
            }
            t0[r] = m0; t1[r] = m1; t2[r] = m2;
        }
    }
    if (cl == 0) {
#pragma unroll
        for (int r = 0; r < 4; ++r) {
            int il = wid * 16 + g * 4 + r;
            if (il < m) {
                int gi = marr[il];
                float* dst = ptop + ((size_t)q * N + gi) * 3;
                dst[0] = t0[r]; dst[1] = t1[r]; dst[2] = t2[r];
            }
        }
    }
}

// ---------------- push: first-arrival table build + bf16 MFMA Gram + chord epilogue + finalize ----------------
template<int USEXB>
__global__ __launch_bounds__(256) void push_gemm_kernel(const float* __restrict__ X,
                                                        const __hip_bfloat16* __restrict__ Xb,
                                                        const float* __restrict__ x2,
                                                        const int* __restrict__ labels,
                                                        const int* __restrict__ cnt,
                                                        const float* __restrict__ ptop,
                                                        float* __restrict__ fv_g,
                                                        float* __restrict__ hdr,
                                                        float* __restrict__ pp,
                                                        unsigned int* __restrict__ tickets,
                                                        double* __restrict__ accd,
                                                        float* __restrict__ out) {
    __shared__ __align__(16) char smem[32768];
    __shared__ __align__(16) float fvP[NB2 + 1];
    __shared__ float x2r[128], x2c[128];
    __shared__ float red[256];
    __shared__ double wsumD[4];
    __shared__ int lastFlag;
    __shared__ int bFlag;
    __shared__ int ibx[4];

    int bid = blockIdx.x;
    int by = 0, rem = bid;
    while (rem >= 32 - by) { rem -= 32 - by; ++by; }
    int bx = by + rem;
    int rowBase = by * 128, colBase = bx * 128;

    int tid = threadIdx.x;
    int lane = tid & 63;
    int wv = tid >> 6;
    int wy = wv >> 1, wx = wv & 1;

    if (tid == 0) bFlag = (atomicAdd(&tickets[2], 1u) == 0u) ? 1 : 0;
    if (tid < 128) { x2r[tid] = x2[rowBase + tid]; x2c[tid] = x2[colBase + tid]; }
    __syncthreads();

    // ---- first-arrival block builds the f-table (exactly one build, device-wide) ----
    if (bFlag) {
        float* radbuf = (float*)smem;            // 16 KB
        int* cntb = (int*)(smem + 16384);        // 8 KB
        float* sumb = (float*)(smem + 24576);    // 8 KB

        // phase A: merge quarter-partials -> radii; local min/max; zero bins
        float mnl = FLT_MAX, mxl = -FLT_MAX;
        for (int s = 0; s < 16; ++s) {
            int i = tid + s * 256;
            int c = labels[i];
            int m = cnt[c];
            int nq = min(4, (m + 31) >> 5);
            const float* p0 = ptop + (size_t)i * 3;
            float a0 = p0[0], a1 = p0[1], a2 = p0[2];
            for (int qq = 1; qq < nq; ++qq) {
                const float* pq = ptop + ((size_t)qq * N + i) * 3;
                merge3(a0, a1, a2, pq[0], pq[1], pq[2]);
            }
            float r = 1.f + a2;
            radbuf[i] = r;
            mnl = fminf(mnl, r);
            mxl = fmaxf(mxl, r);
        }
        {
            int4 zz = {0, 0, 0, 0};
            int4* z4 = (int4*)(smem + 16384);
            z4[tid] = zz; z4[tid + 256] = zz; z4[tid + 512] = zz; z4[tid + 768] = zz;
        }
#pragma unroll
        for (int off = 32; off > 0; off >>= 1) {
            mnl = fminf(mnl, __shfl_xor(mnl, off, 64));
            mxl = fmaxf(mxl, __shfl_xor(mxl, off, 64));
        }
        if (lane == 0) { red[wv] = mnl; red[8 + wv] = mxl; }
        __syncthreads();
        float mn = fminf(fminf(red[0], red[1]), fminf(red[2], red[3]));
        float mx = fmaxf(fmaxf(red[8], red[9]), fmaxf(red[10], red[11]));
        float range = fmaxf(mx - mn, 1e-30f);
        float scale = (float)NB2 / range * (1.f - 1e-6f);
        float wbin = range / (float)NB2;

        // phase B: histogram (count + sum)
        for (int s = 0; s < 16; ++s) {
            float v = radbuf[tid + s * 256];
            int b = max(0, min((int)((v - mn) * scale), NB2 - 1));
            atomicAdd(&cntb[b], 1);
            atomicAdd(&sumb[b], v);
        }
        __syncthreads();

        // phase C: suffix scan, 8 bins/thread (R9-verified scheme)
        int ci[8]; float si[8];
        int Ct = 0; float St = 0.f;
        int base = tid * 8;
#pragma unroll
        for (int k = 0; k < 8; ++k) {
            ci[k] = cntb[base + k]; si[k] = sumb[base + k];
            Ct += ci[k]; St += si[k];
        }
        int sci = Ct; float scf = St;
#pragma unroll
        for (int off = 1; off < 64; off <<= 1) {
            int yi = __shfl_down(sci, off, 64);
            float yf = __shfl_down(scf, off, 64);
            if (lane + off < 64) { sci += yi; scf += yf; }
        }
        __syncthreads();    // red reads (mn/mx) done
        if (lane == 0) { ibx[wv] = sci; red[wv] = scf; }
        __syncthreads();
        int aC = 0; float aS = 0.f;
        for (int w2 = wv + 1; w2 < 4; ++w2) { aC += ibx[w2]; aS += red[w2]; }
        int runC = aC + (sci - Ct);
        float runS = aS + (scf - St);
#pragma unroll
        for (int k = 7; k >= 0; --k) {
            runC += ci[k]; runS += si[k];
            float xe = mn + wbin * (float)(base + k);
            float f = runS - xe * (float)runC;
            fvP[base + k] = f;
            fv_g[base + k] = f;
        }
        if (tid == 0) { fvP[NB2] = 0.f; fv_g[NB2] = 0.f; }
        __syncthreads();

        float Stot = fvP[0] + mn * (float)N;
        float invw = (float)NB2 / fmaxf(mx - mn, 1e-20f);

        // phase D: pull + chord neighbor-subtraction (re-merge ptop)
        float loc = 0.f, pul = 0.f;
        for (int s = 0; s < 16; ++s) {
            int i = tid + s * 256;
            int c = labels[i];
            int m = cnt[c];
            int nq = min(4, (m + 31) >> 5);
            const float* p0 = ptop + (size_t)i * 3;
            float a0 = p0[0], a1 = p0[1], a2 = p0[2];
            for (int qq = 1; qq < nq; ++qq) {
                const float* pq = ptop + ((size_t)qq * N + i) * 3;
                merge3(a0, a1, a2, pq[0], pq[1], pq[2]);
            }
            float tdv[3] = {a0, a1, a2};
#pragma unroll
            for (int k = 0; k < 3; ++k) {
                float d = tdv[k];
                pul += d;
                if (d >= mx) continue;
                if (d < mn) {
                    loc += fmaf(-d, (float)N, Stot);
                } else {
                    float tpos = (d - mn) * invw;
                    int b = min((int)tpos, NB2 - 1);
                    float frac = tpos - (float)b;
                    loc += fmaf(frac, fvP[b + 1] - fvP[b], fvP[b]);
                }
            }
        }
#pragma unroll
        for (int off = 32; off > 0; off >>= 1) {
            loc += __shfl_xor(loc, off, 64);
            pul += __shfl_xor(pul, off, 64);
        }
        __syncthreads();
        if (lane == 0) { red[wv] = loc; red[8 + wv] = pul; }
        __syncthreads();
        if (tid == 0) {
            float s = red[0] + red[1] + red[2] + red[3];
            float p = red[8] + red[9] + red[10] + red[11];
            accd[2] = (double)s;
            accd[0] = (double)p;
            hdr[0] = mn;
            hdr[1] = mx;
            hdr[2] = invw;
            hdr[3] = Stot;
        }
        __syncthreads();
        if (tid == 0) {
            __threadfence();
            atomicExch(&tickets[3], 1u);
        }
        __syncthreads();   // smem free for GEMM staging
    }

    floatx4 acc4[4][4];
#pragma unroll
    for (int m = 0; m < 4; ++m)
#pragma unroll
        for (int n = 0; n < 4; ++n) acc4[m][n] = (floatx4){0.f, 0.f, 0.f, 0.f};

    for (int k0 = 0; k0 < DF; k0 += 64) {
        if (k0) __syncthreads();
        if (USEXB) {
            const __hip_bfloat16* Ab = Xb + (size_t)rowBase * DF;
            const __hip_bfloat16* Bb = Xb + (size_t)colBase * DF;
#pragma unroll
            for (int i = 0; i < 4; ++i) {
                int did = wv * 256 + i * 64 + lane;
                int row = ((did >> 7) << 4) | (did & 15);
                int kb = (did >> 4) & 7;
                size_t goff = (size_t)row * DF + k0 + kb * 8;
                char* ldsA = smem + (size_t)(wv * 256 + i * 64) * 16;
                gload_lds16(Ab + goff, ldsA);
                gload_lds16(Bb + goff, ldsA + 16384);
            }
        } else {
#pragma unroll
            for (int cch = 0; cch < 4; ++cch) {
                int did = tid + (cch << 8);
                int row = ((did >> 7) << 4) | (did & 15);
                int kb = (did >> 4) & 7;
                const float* srcA = X + (size_t)(rowBase + row) * DF + k0 + kb * 8;
                const float* srcB = X + (size_t)(colBase + row) * DF + k0 + kb * 8;
                float4 a0 = *(const float4*)srcA;
                float4 a1 = *(const float4*)(srcA + 4);
                float4 e0 = *(const float4*)srcB;
                float4 e1 = *(const float4*)(srcB + 4);
                ushort8v va, vb;
                va[0] = f2bf(a0.x); va[1] = f2bf(a0.y); va[2] = f2bf(a0.z); va[3] = f2bf(a0.w);
                va[4] = f2bf(a1.x); va[5] = f2bf(a1.y); va[6] = f2bf(a1.z); va[7] = f2bf(a1.w);
                vb[0] = f2bf(e0.x); vb[1] = f2bf(e0.y); vb[2] = f2bf(e0.z); vb[3] = f2bf(e0.w);
                vb[4] = f2bf(e1.x); vb[5] = f2bf(e1.y); vb[6] = f2bf(e1.z); vb[7] = f2bf(e1.w);
                *((ushort8v*)(smem + (did << 4))) = va;
                *((ushort8v*)(smem + 16384 + (did << 4))) = vb;
            }
        }
        __syncthreads();
#pragma unroll
        for (int kk = 0; kk < 2; ++kk) {
            short8v a[4], b[4];
#pragma unroll
            for (int m = 0; m < 4; ++m)
                a[m] = *((const short8v*)(smem + (((wy * 4 + m) * 2 + kk) << 10) + (lane << 4)));
#pragma unroll
            for (int n = 0; n < 4; ++n)
                b[n] = *((const short8v*)(smem + 16384 + (((wx * 4 + n) * 2 + kk) << 10) + (lane << 4)));
#pragma unroll
            for (int m = 0; m < 4; ++m)
#pragma unroll
                for (int n = 0; n < 4; ++n)
                    acc4[m][n] = __builtin_amdgcn_mfma_f32_16x16x32_bf16(a[m], b[n], acc4[m][n], 0, 0, 0);
        }
    }
    __syncthreads();

    // wait for the table (builder finishes long before most GEMMs; spin is ~0)
    if (tid == 0) {
        while (atomicOr(&tickets[3], 0u) == 0u) {
            __builtin_amdgcn_s_sleep(8);
        }
    }
    __syncthreads();
    for (int i = tid; i <= NB2; i += 256) fvP[i] = fv_g[i];
    __syncthreads();

    float d0v = hdr[0], rmaxv = hdr[1], invw = hdr[2], Stot = hdr[3];
    bool diag = (by == bx);

    float local = 0.f;
    int g = lane >> 4;
    int cl = lane & 15;
#pragma unroll
    for (int m = 0; m < 4; ++m) {
#pragma unroll
        for (int n = 0; n < 4; ++n) {
            floatx4 v = acc4[m][n];
            int gcl = wx * 64 + n * 16 + cl;
            float x2cv = x2c[gcl];
#pragma unroll
            for (int r = 0; r < 4; ++r) {
                int grl = wy * 64 + m * 16 + g * 4 + r;
                if (diag && grl == gcl) continue;
                float d = fmaxf(x2r[grl] + x2cv - 2.f * v[r], 0.f);
                if (d >= rmaxv) continue;
                if (d < d0v) {
                    local += fmaf(-d, (float)N, Stot);
                } else {
                    float tpos = (d - d0v) * invw;
                    int b = min((int)tpos, NB2 - 1);
                    float frac = tpos - (float)b;
                    float fa = fvP[b];
                    float fb = fvP[b + 1];
                    local += fmaf(frac, fb - fa, fa);
                }
            }
        }
    }
    red[tid] = local;
    __syncthreads();
    for (int s2 = 128; s2 > 0; s2 >>= 1) {
        if (tid < s2) red[tid] += red[tid + s2];
        __syncthreads();
    }
    if (tid == 0) {
        float wt = diag ? 1.f : 2.f;
        pp[bid] = wt * red[0];
        __threadfence();
        unsigned int old = atomicAdd(&tickets[1], 1u);
        lastFlag = (old == NPUSHBLK - 1) ? 1 : 0;
    }
    __syncthreads();

    if (lastFlag) {
        __threadfence();
        double s = 0.0;
        for (int i = tid; i < NPUSHBLK; i += 256) s += (double)pp[i];
#pragma unroll
        for (int off = 32; off > 0; off >>= 1) s += __shfl_down(s, off, 64);
        if (lane == 0) wsumD[wv] = s;
        __syncthreads();
        if (tid == 0) {
            double tot = wsumD[0] + wsumD[1] + wsumD[2] + wsumD[3];
            out[0] = (float)((accd[0] + tot - accd[2]) / (double)N);
        }
    }
}

extern "C" void kernel_launch(void* const* d_in, const int* in_sizes, int n_in,
                              void* d_out, int out_size, void* d_ws, size_t ws_size,
                              hipStream_t stream) {
    const float* X = (const float*)d_in[0];
    const int* labels = (const int*)d_in[1];
    float* out = (float*)d_out;

    char* w = (char*)d_ws;
    double* accd   = (double*)w;                         // 64 B
    float* x2      = (float*)(w + 64);                   // 16 KB
    float* ptop    = (float*)(w + 16448);                // 192 KB
    int* cnt       = (int*)(w + 213056);                 // 256 B
    int* members   = (int*)(w + 213312);                 // 64 KB
    float* hdr     = (float*)(w + 278848);               // 64 B
    float* fv_g    = (float*)(w + 278912);               // 8.2 KB (2049 floats)
    float* pp      = (float*)(w + 287168);               // 2112 B
    unsigned int* tickets = (unsigned int*)(w + 289280); // 64 B
    __hip_bfloat16* Xb = (__hip_bfloat16*)(w + 289344);  // 2 MB
    size_t need_xb = 289344 + (size_t)N * DF * 2;
    int useXb = (ws_size >= need_xb) ? 1 : 0;

    hipLaunchKernelGGL(prep_kernel, dim3(1025), dim3(256), 0, stream,
                       X, labels, x2, Xb, cnt, members, accd, tickets, useXb);
    hipLaunchKernelGGL(knn4_kernel, dim3(256), dim3(512), 0, stream,
                       X, x2, cnt, members, ptop);
    if (useXb)
        hipLaunchKernelGGL(push_gemm_kernel<1>, dim3(NPUSHBLK), dim3(256), 0, stream,
                           X, Xb, x2, labels, cnt, ptop, fv_g, hdr, pp, tickets, accd, out);
    else
        hipLaunchKernelGGL(push_gemm_kernel<0>, dim3(NPUSHBLK), dim3(256), 0, stream,
                           X, Xb, x2, labels, cnt, ptop, fv_g, hdr, pp, tickets, accd, out);
}

// Round 15
// 66.081 us; speedup vs baseline: 1.4456x; 1.4456x over previous
//
#include <hip/hip_runtime.h>
#include <hip/hip_bf16.h>
#include <float.h>

#define N 4096
#define DF 256
#define NB2 2048
#define MAXM 128
#define NPUSHBLK 528

typedef __attribute__((ext_vector_type(8))) short short8v;
typedef __attribute__((ext_vector_type(8))) unsigned short ushort8v;
typedef __attribute__((ext_vector_type(4))) float floatx4;

__device__ inline unsigned short f2bf(float f) {
    __hip_bfloat16 h = __float2bfloat16(f);
    return *reinterpret_cast<unsigned short*>(&h);
}
__device__ inline float bf2f(unsigned short h) {
    unsigned int u = ((unsigned int)h) << 16;
    return __uint_as_float(u);
}

__device__ inline void gload_lds16(const void* g, void* l) {
    __builtin_amdgcn_global_load_lds((const __attribute__((address_space(1))) void*)g,
                                     (__attribute__((address_space(3))) void*)l, 16, 0, 0);
}

// ---------------- prep: x2 norms + bf16 convert + (extra block) class bucketing ----------------
__global__ __launch_bounds__(256) void prep_kernel(const float* __restrict__ X,
                                                   const int* __restrict__ labels,
                                                   float* __restrict__ x2,
                                                   __hip_bfloat16* __restrict__ Xb,
                                                   int* __restrict__ cnt,
                                                   int* __restrict__ members,
                                                   double* __restrict__ accd,
                                                   unsigned int* __restrict__ tickets,
                                                   int useXb) {
    int t = threadIdx.x;
    if (blockIdx.x == 1024) {
        __shared__ int scnt[64];
        if (t < 8) accd[t] = 0.0;
        if (t == 8) { tickets[0] = 0u; tickets[1] = 0u; }
        if (t < 64) scnt[t] = 0;
        __syncthreads();
        for (int i = t; i < N; i += 256) {
            int c = labels[i];
            int pos = atomicAdd(&scnt[c], 1);
            if (pos < MAXM) members[(c << 8) + pos] = i;
        }
        __syncthreads();
        if (t < 64) cnt[t] = min(scnt[t], MAXM);
        return;
    }
    int row = blockIdx.x * 4 + (t >> 6);
    int l = t & 63;
    int idx = row * 64 + l;
    float4 v = ((const float4*)X)[idx];
    if (useXb) {
        ushort4 o;
        o.x = f2bf(v.x); o.y = f2bf(v.y); o.z = f2bf(v.z); o.w = f2bf(v.w);
        ((ushort4*)Xb)[idx] = o;
    }
    float s = v.x * v.x + v.y * v.y + v.z * v.z + v.w * v.w;
#pragma unroll
    for (int off = 32; off > 0; off >>= 1) s += __shfl_xor(s, off, 64);
    if (l == 0) x2[row] = s;
}

// ---------------- per-(class, col-quarter) partial 3-NN via hi/lo bf16 MFMA ----------------
__device__ inline void top3_upd(float& b0, float& b1, float& b2, float dd) {
    if (dd < b2) {
        if (dd < b1) { b2 = b1; if (dd < b0) { b1 = b0; b0 = dd; } else b1 = dd; }
        else b2 = dd;
    }
}

__global__ __launch_bounds__(512) void knn4_kernel(const float* __restrict__ X,
                                                   const float* __restrict__ x2,
                                                   const int* __restrict__ cnt,
                                                   const int* __restrict__ members,
                                                   float* __restrict__ ptop) {
    __shared__ __align__(16) char smem[32768];   // Hi 16 KB + Lo 16 KB (32 member rows)
    __shared__ int marr[MAXM];
    __shared__ float mx2[MAXM];

    int c = blockIdx.x & 63;
    int q = blockIdx.x >> 6;          // 0..3 column quarter
    int m = cnt[c];
    if (q * 32 >= m) return;          // block-uniform
    const int* mem = members + (c << 8);
    int tid = threadIdx.x;
    int lane = tid & 63;
    int wid = tid >> 6;
    int qbase = q * 32;

    if (tid < MAXM) {
        int mi = (tid < m) ? mem[tid] : -1;
        marr[tid] = mi;
        mx2[tid] = (mi >= 0) ? x2[mi] : 0.f;
    }
    __syncthreads();

    char* Hi = smem;
    char* Lo = smem + 16384;

#pragma unroll
    for (int it = 0; it < 2; ++it) {
        int idx = it * 512 + tid;
        int rb = idx >> 9;
        int rem = idx & 511;
        int kb = rem >> 4;
        int r0 = rem & 15;
        int rg = qbase + rb * 16 + r0;
        ushort8v vhi = (ushort8v){0,0,0,0,0,0,0,0};
        ushort8v vlo = vhi;
        if (rg < m) {
            const float4* src = (const float4*)(X + (size_t)marr[rg] * DF + kb * 8);
            float4 u0 = src[0], u1 = src[1];
            float uu[8] = {u0.x, u0.y, u0.z, u0.w, u1.x, u1.y, u1.z, u1.w};
#pragma unroll
            for (int p = 0; p < 8; ++p) {
                unsigned short h = f2bf(uu[p]);
                vhi[p] = h;
                vlo[p] = f2bf(uu[p] - bf2f(h));
            }
        }
        *((ushort8v*)(Hi + ((size_t)idx << 4))) = vhi;
        *((ushort8v*)(Lo + ((size_t)idx << 4))) = vlo;
    }
    __syncthreads();

    int nstripe = (m + 15) >> 4;
    if (wid >= nstripe) return;

    int arow = wid * 16 + (lane & 15);
    bool avalid = (arow < m);
    const float* aptr = X + (size_t)(avalid ? marr[arow] : 0) * DF;
    int ko = (lane >> 4) * 8;
    short8v aHi[8], aLo[8];
#pragma unroll
    for (int kk = 0; kk < 8; ++kk) {
        ushort8v vhi = (ushort8v){0,0,0,0,0,0,0,0};
        ushort8v vlo = vhi;
        if (avalid) {
            const float* p0 = aptr + kk * 32 + ko;
            float4 u0 = *(const float4*)p0;
            float4 u1 = *(const float4*)(p0 + 4);
            float uu[8] = {u0.x, u0.y, u0.z, u0.w, u1.x, u1.y, u1.z, u1.w};
#pragma unroll
            for (int p = 0; p < 8; ++p) {
                unsigned short h = f2bf(uu[p]);
                vhi[p] = h;
                vlo[p] = f2bf(uu[p] - bf2f(h));
            }
        }
        aHi[kk] = *(short8v*)&vhi;
        aLo[kk] = *(short8v*)&vlo;
    }

    int g = lane >> 4;
    int cl = lane & 15;
    float x2i[4];
#pragma unroll
    for (int r = 0; r < 4; ++r) {
        int il = wid * 16 + g * 4 + r;
        x2i[r] = mx2[il];
    }

    float t0[4], t1[4], t2[4];
#pragma unroll
    for (int r = 0; r < 4; ++r) { t0[r] = FLT_MAX; t1[r] = FLT_MAX; t2[r] = FLT_MAX; }

#pragma unroll
    for (int ct = 0; ct < 2; ++ct) {
        floatx4 acc = (floatx4){0.f, 0.f, 0.f, 0.f};
#pragma unroll
        for (int kk = 0; kk < 8; ++kk) {
            size_t off = (size_t)ct * 8192 + (size_t)kk * 1024 + ((size_t)lane << 4);
            short8v bHi = *((const short8v*)(Hi + off));
            short8v bLo = *((const short8v*)(Lo + off));
            acc = __builtin_amdgcn_mfma_f32_16x16x32_bf16(aLo[kk], bHi, acc, 0, 0, 0);
            acc = __builtin_amdgcn_mfma_f32_16x16x32_bf16(aHi[kk], bLo, acc, 0, 0, 0);
            acc = __builtin_amdgcn_mfma_f32_16x16x32_bf16(aHi[kk], bHi, acc, 0, 0, 0);
        }
        int jg = qbase + ct * 16 + cl;
        float x2j = (jg < MAXM) ? mx2[jg] : 0.f;
#pragma unroll
        for (int r = 0; r < 4; ++r) {
            int il = wid * 16 + g * 4 + r;
            float d = fmaxf(x2i[r] + x2j - 2.f * acc[r], 0.f);
            bool valid = (jg < m) && (il < m) && (jg != il);
            top3_upd(t0[r], t1[r], t2[r], valid ? d : FLT_MAX);
        }
    }

#pragma unroll
    for (int off = 1; off <= 8; off <<= 1) {
#pragma unroll
        for (int r = 0; r < 4; ++r) {
            float c0 = __shfl_xor(t0[r], off, 64);
            float c1 = __shfl_xor(t1[r], off, 64);
            float c2 = __shfl_xor(t2[r], off, 64);
            float m0, m1, m2;
            if (t0[r] <= c0) {
                m0 = t0[r];
                if (t1[r] <= c0) { m1 = t1[r]; m2 = fminf(t2[r], c0); }
                else { m1 = c0; m2 = fminf(t1[r], c1); }
            } else {
                m0 = c0;
                if (c1 <= t0[r]) { m1 = c1; m2 = fminf(c2, t0[r]); }
                else { m1 = t0[r]; m2 = fminf(c1, t1[r]); }
            }
            t0[r] = m0; t1[r] = m1; t2[r] = m2;
        }
    }
    if (cl == 0) {
#pragma unroll
        for (int r = 0; r < 4; ++r) {
            int il = wid * 16 + g * 4 + r;
            if (il < m) {
                int gi = marr[il];
                float* dst = ptop + ((size_t)q * N + gi) * 3;
                dst[0] = t0[r]; dst[1] = t1[r]; dst[2] = t2[r];
            }
        }
    }
}

// ---------------- merge partials + histogram(2048) + f-table + pull + neighbor subtract ----------------
__global__ __launch_bounds__(1024) void histo_ftab_kernel(const int* __restrict__ labels,
                                                          const int* __restrict__ cnt,
                                                          const float* __restrict__ ptop,
                                                          float* __restrict__ fv_g,
                                                          float* __restrict__ hdr,
                                                          double* __restrict__ accd) {
    __shared__ int cntb[NB2];
    __shared__ float sumb[NB2];
    __shared__ float fv[NB2 + 1];
    __shared__ float aux[64];
    __shared__ int iaux[16];
    int t = threadIdx.x;
    int wid = t >> 6, lane = t & 63;

    // merge the <=4 quarter-partials for samples t, t+1024, t+2048, t+3072
    float rad[4];
    float td[4][3];
#pragma unroll
    for (int s = 0; s < 4; ++s) {
        int i = t + s * 1024;
        int c = labels[i];
        int m = cnt[c];
        int nq = min(4, (m + 31) >> 5);
        const float* p0 = ptop + (size_t)i * 3;
        float a0 = p0[0], a1 = p0[1], a2 = p0[2];
        for (int qq = 1; qq < nq; ++qq) {
            const float* pq = ptop + ((size_t)qq * N + i) * 3;
            float b0 = pq[0], b1 = pq[1], b2 = pq[2];
            float m0, m1, m2;
            if (a0 <= b0) {
                m0 = a0;
                if (a1 <= b0) { m1 = a1; m2 = fminf(a2, b0); }
                else { m1 = b0; m2 = fminf(a1, b1); }
            } else {
                m0 = b0;
                if (b1 <= a0) { m1 = b1; m2 = fminf(b2, a0); }
                else { m1 = a0; m2 = fminf(b1, a1); }
            }
            a0 = m0; a1 = m1; a2 = m2;
        }
        td[s][0] = a0; td[s][1] = a1; td[s][2] = a2;
        rad[s] = 1.f + a2;
    }

    float mn = fminf(fminf(rad[0], rad[1]), fminf(rad[2], rad[3]));
    float mx = fmaxf(fmaxf(rad[0], rad[1]), fmaxf(rad[2], rad[3]));
#pragma unroll
    for (int off = 32; off > 0; off >>= 1) {
        mn = fminf(mn, __shfl_xor(mn, off, 64));
        mx = fmaxf(mx, __shfl_xor(mx, off, 64));
    }
    if (lane == 0) { aux[wid] = mn; aux[wid + 16] = mx; }
    cntb[t] = 0; cntb[t + 1024] = 0;
    sumb[t] = 0.f; sumb[t + 1024] = 0.f;
    __syncthreads();
    mn = aux[0]; mx = aux[16];
    for (int w = 1; w < 16; ++w) { mn = fminf(mn, aux[w]); mx = fmaxf(mx, aux[w + 16]); }
    float range = fmaxf(mx - mn, 1e-30f);
    float scale = (float)NB2 / range * (1.f - 1e-6f);

#pragma unroll
    for (int s = 0; s < 4; ++s) {
        int b = max(0, min((int)((rad[s] - mn) * scale), NB2 - 1));
        atomicAdd(&cntb[b], 1);
        atomicAdd(&sumb[b], rad[s]);
    }
    __syncthreads();

    // suffix scan of (cnt, sum); thread owns bins [2t, 2t+1]
    int c0 = cntb[2 * t], c1 = cntb[2 * t + 1];
    float s0 = sumb[2 * t], s1 = sumb[2 * t + 1];
    int toti = c0 + c1;
    float totf = s0 + s1;
    int sci = toti;
    float scf = totf;
#pragma unroll
    for (int off = 1; off < 64; off <<= 1) {
        int yi = __shfl_down(sci, off, 64);
        float yf = __shfl_down(scf, off, 64);
        if (lane + off < 64) { sci += yi; scf += yf; }
    }
    if (lane == 0) { iaux[wid] = sci; aux[wid] = scf; }
    __syncthreads();
    if (t < 16) {
        int xi = iaux[t];
        float xf = aux[t];
        int si = xi;
        float sf = xf;
#pragma unroll
        for (int off = 1; off < 16; off <<= 1) {
            int yi = __shfl_down(si, off, 64);
            float yf = __shfl_down(sf, off, 64);
            if (t + off < 16) { si += yi; sf += yf; }
        }
        iaux[t] = si - xi;
        aux[t] = sf - xf;
    }
    __syncthreads();
    int afteri = iaux[wid] + (sci - toti);
    float afterf = aux[wid] + (scf - totf);
    int C1 = c1 + afteri, C0 = c0 + C1;
    float S1 = s1 + afterf, S0 = s0 + S1;

    float wbin = range / (float)NB2;
    {
        float x0 = mn + wbin * (float)(2 * t);
        fv[2 * t + 0] = S0 - x0 * (float)C0;
        float x1 = mn + wbin * (float)(2 * t + 1);
        fv[2 * t + 1] = S1 - x1 * (float)C1;
    }
    if (t == 0) fv[NB2] = 0.f;
    __syncthreads();

    for (int b = t; b <= NB2; b += 1024)
        fv_g[b] = fv[b];
    float Stot = fv[0] + mn * (float)N;
    float invw = (float)NB2 / fmaxf(mx - mn, 1e-20f);
    if (t == 0) {
        hdr[0] = mn;
        hdr[1] = mx;
        hdr[2] = invw;
        hdr[3] = Stot;
    }

    // pull + chord-based neighbor-pair subtraction (from registers)
    float loc = 0.f, pul = 0.f;
#pragma unroll
    for (int s = 0; s < 4; ++s) {
#pragma unroll
        for (int k = 0; k < 3; ++k) {
            float d = td[s][k];
            pul += d;
            if (d >= mx) continue;
            if (d < mn) {
                loc += fmaf(-d, (float)N, Stot);
            } else {
                float tpos = (d - mn) * invw;
                int b = min((int)tpos, NB2 - 1);
                float frac = tpos - (float)b;
                loc += fmaf(frac, fv[b + 1] - fv[b], fv[b]);
            }
        }
    }
#pragma unroll
    for (int off = 32; off > 0; off >>= 1) {
        loc += __shfl_xor(loc, off, 64);
        pul += __shfl_xor(pul, off, 64);
    }
    __syncthreads();
    if (lane == 0) { aux[wid] = loc; aux[wid + 16] = pul; }
    __syncthreads();
    if (t == 0) {
        float s = 0.f, p = 0.f;
        for (int w = 0; w < 16; ++w) { s += aux[w]; p += aux[w + 16]; }
        accd[2] = (double)s;
        accd[0] = (double)p;
    }
}

// ---------------- fused bf16 MFMA Gram + chord epilogue (table preloaded) + last-block finalize ----------------
template<int USEXB>
__global__ __launch_bounds__(256) void push_gemm_kernel(const float* __restrict__ X,
                                                        const __hip_bfloat16* __restrict__ Xb,
                                                        const float* __restrict__ x2,
                                                        const float* __restrict__ fv_g,
                                                        const float* __restrict__ hdr,
                                                        float* __restrict__ pp,
                                                        unsigned int* __restrict__ tickets,
                                                        const double* __restrict__ accd,
                                                        float* __restrict__ out) {
    __shared__ __align__(16) char smem[32768];
    __shared__ __align__(16) float fvP[NB2 + 1];
    __shared__ float x2r[128], x2c[128];
    __shared__ float red[256];
    __shared__ double wsumD[4];
    __shared__ int lastFlag;

    int bid = blockIdx.x;
    int by = 0, rem = bid;
    while (rem >= 32 - by) { rem -= 32 - by; ++by; }
    int bx = by + rem;
    int rowBase = by * 128, colBase = bx * 128;

    int tid = threadIdx.x;
    int lane = tid & 63;
    int wv = tid >> 6;
    int wy = wv >> 1, wx = wv & 1;

    floatx4 acc4[4][4];
#pragma unroll
    for (int m = 0; m < 4; ++m)
#pragma unroll
        for (int n = 0; n < 4; ++n) acc4[m][n] = (floatx4){0.f, 0.f, 0.f, 0.f};

    if (tid < 128) { x2r[tid] = x2[rowBase + tid]; x2c[tid] = x2[colBase + tid]; }
    // preload the f-table (overlaps with GEMM staging; consumed after last barrier)
    for (int i = tid; i <= NB2; i += 256) fvP[i] = fv_g[i];

    for (int k0 = 0; k0 < DF; k0 += 64) {
        if (k0) __syncthreads();
        if (USEXB) {
            const __hip_bfloat16* Ab = Xb + (size_t)rowBase * DF;
            const __hip_bfloat16* Bb = Xb + (size_t)colBase * DF;
#pragma unroll
            for (int i = 0; i < 4; ++i) {
                int did = wv * 256 + i * 64 + lane;
                int row = ((did >> 7) << 4) | (did & 15);
                int kb = (did >> 4) & 7;
                size_t goff = (size_t)row * DF + k0 + kb * 8;
                char* ldsA = smem + (size_t)(wv * 256 + i * 64) * 16;
                gload_lds16(Ab + goff, ldsA);
                gload_lds16(Bb + goff, ldsA + 16384);
            }
        } else {
#pragma unroll
            for (int cch = 0; cch < 4; ++cch) {
                int did = tid + (cch << 8);
                int row = ((did >> 7) << 4) | (did & 15);
                int kb = (did >> 4) & 7;
                const float* srcA = X + (size_t)(rowBase + row) * DF + k0 + kb * 8;
                const float* srcB = X + (size_t)(colBase + row) * DF + k0 + kb * 8;
                float4 a0 = *(const float4*)srcA;
                float4 a1 = *(const float4*)(srcA + 4);
                float4 e0 = *(const float4*)srcB;
                float4 e1 = *(const float4*)(srcB + 4);
                ushort8v va, vb;
                va[0] = f2bf(a0.x); va[1] = f2bf(a0.y); va[2] = f2bf(a0.z); va[3] = f2bf(a0.w);
                va[4] = f2bf(a1.x); va[5] = f2bf(a1.y); va[6] = f2bf(a1.z); va[7] = f2bf(a1.w);
                vb[0] = f2bf(e0.x); vb[1] = f2bf(e0.y); vb[2] = f2bf(e0.z); vb[3] = f2bf(e0.w);
                vb[4] = f2bf(e1.x); vb[5] = f2bf(e1.y); vb[6] = f2bf(e1.z); vb[7] = f2bf(e1.w);
                *((ushort8v*)(smem + (did << 4))) = va;
                *((ushort8v*)(smem + 16384 + (did << 4))) = vb;
            }
        }
        __syncthreads();
#pragma unroll
        for (int kk = 0; kk < 2; ++kk) {
            short8v a[4], b[4];
#pragma unroll
            for (int m = 0; m < 4; ++m)
                a[m] = *((const short8v*)(smem + (((wy * 4 + m) * 2 + kk) << 10) + (lane << 4)));
#pragma unroll
            for (int n = 0; n < 4; ++n)
                b[n] = *((const short8v*)(smem + 16384 + (((wx * 4 + n) * 2 + kk) << 10) + (lane << 4)));
#pragma unroll
            for (int m = 0; m < 4; ++m)
#pragma unroll
                for (int n = 0; n < 4; ++n)
                    acc4[m][n] = __builtin_amdgcn_mfma_f32_16x16x32_bf16(a[m], b[n], acc4[m][n], 0, 0, 0);
        }
    }
    __syncthreads();

    float d0v = hdr[0], rmaxv = hdr[1], invw = hdr[2], Stot = hdr[3];
    bool diag = (by == bx);

    float local = 0.f;
    int g = lane >> 4;
    int cl = lane & 15;
#pragma unroll
    for (int m = 0; m < 4; ++m) {
#pragma unroll
        for (int n = 0; n < 4; ++n) {
            floatx4 v = acc4[m][n];
            int gcl = wx * 64 + n * 16 + cl;
            float x2cv = x2c[gcl];
#pragma unroll
            for (int r = 0; r < 4; ++r) {
                int grl = wy * 64 + m * 16 + g * 4 + r;
                if (diag && grl == gcl) continue;
                float d = fmaxf(x2r[grl] + x2cv - 2.f * v[r], 0.f);
                if (d >= rmaxv) continue;
                if (d < d0v) {
                    local += fmaf(-d, (float)N, Stot);
                } else {
                    float tpos = (d - d0v) * invw;
                    int b = min((int)tpos, NB2 - 1);
                    float frac = tpos - (float)b;
                    float fa = fvP[b];
                    float fb = fvP[b + 1];
                    local += fmaf(frac, fb - fa, fa);
                }
            }
        }
    }
    red[tid] = local;
    __syncthreads();
    for (int s2 = 128; s2 > 0; s2 >>= 1) {
        if (tid < s2) red[tid] += red[tid + s2];
        __syncthreads();
    }
    if (tid == 0) {
        float wt = diag ? 1.f : 2.f;
        pp[bid] = wt * red[0];
        __threadfence();
        unsigned int old = atomicAdd(&tickets[1], 1u);
        lastFlag = (old == NPUSHBLK - 1) ? 1 : 0;
    }
    __syncthreads();

    if (lastFlag) {
        __threadfence();
        double s = 0.0;
        for (int i = tid; i < NPUSHBLK; i += 256) s += (double)pp[i];
#pragma unroll
        for (int off = 32; off > 0; off >>= 1) s += __shfl_down(s, off, 64);
        if (lane == 0) wsumD[wv] = s;
        __syncthreads();
        if (tid == 0) {
            double tot = wsumD[0] + wsumD[1] + wsumD[2] + wsumD[3];
            out[0] = (float)((accd[0] + tot - accd[2]) / (double)N);
        }
    }
}

extern "C" void kernel_launch(void* const* d_in, const int* in_sizes, int n_in,
                              void* d_out, int out_size, void* d_ws, size_t ws_size,
                              hipStream_t stream) {
    const float* X = (const float*)d_in[0];
    const int* labels = (const int*)d_in[1];
    float* out = (float*)d_out;

    char* w = (char*)d_ws;
    double* accd   = (double*)w;                         // 64 B
    float* x2      = (float*)(w + 64);                   // 16 KB
    float* ptop    = (float*)(w + 16448);                // 192 KB
    int* cnt       = (int*)(w + 213056);                 // 256 B
    int* members   = (int*)(w + 213312);                 // 64 KB
    float* hdr     = (float*)(w + 278848);               // 64 B
    float* fv_g    = (float*)(w + 278912);               // 8.2 KB (2049 floats)
    float* pp      = (float*)(w + 287168);               // 2112 B
    unsigned int* tickets = (unsigned int*)(w + 289280); // 64 B
    __hip_bfloat16* Xb = (__hip_bfloat16*)(w + 289344);  // 2 MB
    size_t need_xb = 289344 + (size_t)N * DF * 2;
    int useXb = (ws_size >= need_xb) ? 1 : 0;

    hipLaunchKernelGGL(prep_kernel, dim3(1025), dim3(256), 0, stream,
                       X, labels, x2, Xb, cnt, members, accd, tickets, useXb);
    hipLaunchKernelGGL(knn4_kernel, dim3(256), dim3(512), 0, stream,
                       X, x2, cnt, members, ptop);
    hipLaunchKernelGGL(histo_ftab_kernel, dim3(1), dim3(1024), 0, stream,
                       labels, cnt, ptop, fv_g, hdr, accd);
    if (useXb)
        hipLaunchKernelGGL(push_gemm_kernel<1>, dim3(NPUSHBLK), dim3(256), 0, stream,
                           X, Xb, x2, fv_g, hdr, pp, tickets, accd, out);
    else
        hipLaunchKernelGGL(push_gemm_kernel<0>, dim3(NPUSHBLK), dim3(256), 0, stream,
                           X, Xb, x2, fv_g, hdr, pp, tickets, accd, out);
}